// Round 2
// baseline (318.446 us; speedup 1.0000x reference)
//
#include <hip/hip_runtime.h>
#include <stdint.h>

#define Bn 16
#define Gn 128
#define Pn 8000
#define Rn 200
#define POSCAP 66
#define SORTN 8192

// Exact JAX threefry2x32 block (jax/_src/prng.py rotation schedule).
__device__ __forceinline__ void tf2x32(uint32_t k0, uint32_t k1,
                                       uint32_t x0, uint32_t x1,
                                       uint32_t& y0, uint32_t& y1) {
  uint32_t ks0 = k0, ks1 = k1, ks2 = k0 ^ k1 ^ 0x1BD11BDAu;
  x0 += ks0; x1 += ks1;
#define TF_ROUND(r) { x0 += x1; x1 = (x1 << (r)) | (x1 >> (32 - (r))); x1 ^= x0; }
  TF_ROUND(13) TF_ROUND(15) TF_ROUND(26) TF_ROUND(6)
  x0 += ks1; x1 += ks2 + 1u;
  TF_ROUND(17) TF_ROUND(29) TF_ROUND(16) TF_ROUND(24)
  x0 += ks2; x1 += ks0 + 2u;
  TF_ROUND(13) TF_ROUND(15) TF_ROUND(26) TF_ROUND(6)
  x0 += ks0; x1 += ks1 + 3u;
  TF_ROUND(17) TF_ROUND(29) TF_ROUND(16) TF_ROUND(24)
  x0 += ks1; x1 += ks2 + 4u;
  TF_ROUND(13) TF_ROUND(15) TF_ROUND(26) TF_ROUND(6)
  x0 += ks2; x1 += ks0 + 5u;
#undef TF_ROUND
  y0 = x0; y1 = x1;
}

// IoU, bit-exact vs reference float32 (no FMA contraction).
__device__ __forceinline__ float iou_f(float g0, float g1, float g2, float g3, float ag,
                                       float p0, float p1, float p2, float p3) {
  float iw = fmaxf(0.0f, __fsub_rn(fminf(g3, p3), fmaxf(g1, p1)));
  float ih = fmaxf(0.0f, __fsub_rn(fminf(g2, p2), fmaxf(g0, p0)));
  float inter = __fmul_rn(iw, ih);
  float ap = __fmul_rn(__fsub_rn(p3, p1), __fsub_rn(p2, p0));
  return __fdiv_rn(inter, __fsub_rn(__fadd_rn(ag, ap), inter));
}

// Per-(b,g): argmax of IoU over all proposals (tie -> lowest index); scatter removed.
__global__ __launch_bounds__(64) void k_rowmax(const float* __restrict__ gt,
                                               const float* __restrict__ pr,
                                               int* __restrict__ removed) {
  int bg = blockIdx.x;
  int b = bg >> 7, g = bg & 127;
  const float* gb = gt + (size_t)(b * Gn + g) * 5;
  float g0 = gb[0], g1 = gb[1], g2 = gb[2], g3 = gb[3], gv = gb[4];
  if (gv == 0.0f) return;  // invalid GT scatters max(…,0): no-op
  float ag = __fmul_rn(__fsub_rn(g3, g1), __fsub_rn(g2, g0));
  const float* prb = pr + (size_t)b * Pn * 5;
  int lane = threadIdx.x;
  float best = -2.0f; int bidx = 0;
  for (int p = lane; p < Pn; p += 64) {
    const float* pb = prb + (size_t)p * 5;
    float p0 = pb[0], p1 = pb[1], p2 = pb[2], p3 = pb[3], pv = pb[4];
    float v = -1.0f;
    if (pv != 0.0f) v = iou_f(g0, g1, g2, g3, ag, p0, p1, p2, p3);
    if (v > best) { best = v; bidx = p; }  // ascending p => first occurrence
  }
  for (int off = 32; off > 0; off >>= 1) {
    float ov = __shfl_down(best, off);
    int oi = __shfl_down(bidx, off);
    if (ov > best || (ov == best && oi < bidx)) { best = ov; bidx = oi; }
  }
  if (lane == 0) removed[b * Pn + bidx] = 1;
}

// Per-proposal: max/argmax of IoU over GTs (tie -> lowest g).
__global__ __launch_bounds__(256) void k_colstats(const float* __restrict__ gt,
                                                  const float* __restrict__ pr,
                                                  float* __restrict__ pmax,
                                                  int* __restrict__ parg) {
  __shared__ float sg[Gn * 5];
  int b = blockIdx.y;
  for (int i = threadIdx.x; i < Gn * 5; i += blockDim.x)
    sg[i] = gt[(size_t)b * Gn * 5 + i];
  __syncthreads();
  int p = blockIdx.x * blockDim.x + threadIdx.x;
  if (p >= Pn) return;
  const float* pb = pr + ((size_t)b * Pn + p) * 5;
  float p0 = pb[0], p1 = pb[1], p2 = pb[2], p3 = pb[3], pv = pb[4];
  float best = -1.0f; int bidx = 0;  // invalid column: all -1 -> argmax 0
  if (pv != 0.0f) {
    best = -2.0f;
    for (int g = 0; g < Gn; g++) {
      const float* gb = sg + g * 5;
      float v = -1.0f;
      if (gb[4] != 0.0f) {
        float ag = __fmul_rn(__fsub_rn(gb[3], gb[1]), __fsub_rn(gb[2], gb[0]));
        v = iou_f(gb[0], gb[1], gb[2], gb[3], ag, p0, p1, p2, p3);
      }
      if (v > best) { best = v; bidx = g; }
    }
  }
  pmax[b * Pn + p] = best;
  parg[b * Pn + p] = bidx;
}

// Per-batch: PRNG (threefry partitionable), classification, sort-based top-k,
// epilogue, miss.
__global__ __launch_bounds__(1024) void k_select(
    const float* __restrict__ gt, const int* __restrict__ gtc,
    const float* __restrict__ pr, const int* __restrict__ removed,
    const float* __restrict__ pmax, const int* __restrict__ parg,
    float* __restrict__ out) {
  __shared__ uint32_t sk[SORTN];     // (cls<<23)|uniform_bits>>9
  __shared__ uint16_t sidx[SORTN];   // proposal index (tie-break asc)
  __shared__ int matched[Gn];
  __shared__ int s_npos, s_nneg, s_miss;
  __shared__ uint32_t s_keys[4];
  int b = blockIdx.x;
  int tid = threadIdx.x;

  if (tid == 0) {
    // jax_threefry_partitionable=True (modern default):
    //   split(key, n)[i] = tf(key, hi32(i)=0, lo32(i)=i)  (both outputs = new key)
    //   keys = split(key(42)=(0,42), 16); key_b = keys[b]
    //   k1, k2 = split(key_b)  ->  tf(key_b,0,0), tf(key_b,0,1)
    uint32_t kb0, kb1;
    tf2x32(0u, 42u, 0u, (uint32_t)b, kb0, kb1);
    uint32_t a0, a1, c0_, c1_;
    tf2x32(kb0, kb1, 0u, 0u, a0, a1);   // k1
    tf2x32(kb0, kb1, 0u, 1u, c0_, c1_); // k2
    s_keys[0] = a0; s_keys[1] = a1;
    s_keys[2] = c0_; s_keys[3] = c1_;
    s_npos = 0; s_nneg = 0; s_miss = 0;
  }
  for (int i = tid; i < Gn; i += blockDim.x) matched[i] = 0;
  __syncthreads();

  uint32_t k10 = s_keys[0], k11 = s_keys[1], k20 = s_keys[2], k21 = s_keys[3];
  int lpos = 0, lneg = 0;
  const size_t bp = (size_t)b * Pn;

  // random_bits (partitionable, 32-bit): bits[p] = y0 ^ y1 of tf(key, 0, p)
  for (int p = tid; p < Pn; p += blockDim.x) {
    uint32_t a, bb, c, d;
    tf2x32(k10, k11, 0u, (uint32_t)p, a, bb);
    tf2x32(k20, k21, 0u, (uint32_t)p, c, d);
    uint32_t u1 = (a ^ bb) >> 9;  // monotone proxy for uniform value
    uint32_t u2 = (c ^ d) >> 9;
    float pv = pr[(bp + p) * 5 + 4];
    int rem = removed[bp + p];
    float pm = pmax[bp + p];
    int cls = 0;
    if (pv != 0.0f && rem == 0) cls = (pm >= 0.5f) ? 2 : 1;
    uint32_t vb = (cls == 2) ? u1 : ((cls == 1) ? u2 : 0u);
    sk[p] = ((uint32_t)cls << 23) | vb;
    sidx[p] = (uint16_t)p;
    if (cls == 2) { lpos++; matched[parg[bp + p]] = 1; }
    else if (cls == 1) lneg++;
  }
  for (int p = Pn + tid; p < SORTN; p += blockDim.x) { sk[p] = 0u; sidx[p] = (uint16_t)p; }
  if (lpos) atomicAdd(&s_npos, lpos);
  if (lneg) atomicAdd(&s_nneg, lneg);
  __syncthreads();

  // Bitonic sort: total order (value desc, index asc) => unique result,
  // matching lax.top_k stable tie-breaking.
  for (unsigned k = 2; k <= SORTN; k <<= 1) {
    for (unsigned j = k >> 1; j > 0; j >>= 1) {
      for (unsigned i = tid; i < SORTN; i += blockDim.x) {
        unsigned l = i ^ j;
        if (l > i) {
          uint32_t av = sk[i], cv = sk[l];
          uint16_t ai = sidx[i], ci = sidx[l];
          bool a_first = (av > cv) || (av == cv && ai < ci);
          bool desc = ((i & k) == 0u);
          if (desc != a_first) { sk[i] = cv; sk[l] = av; sidx[i] = ci; sidx[l] = ai; }
        }
      }
      __syncthreads();
    }
  }

  int npos = s_npos, nneg = s_nneg;
  int n_pos = npos < POSCAP ? npos : POSCAP;
  int rem_slots = Rn - n_pos;
  int n_neg = nneg < rem_slots ? nneg : rem_slots;

  float* o_del = out;
  float* o_cls = out + (size_t)Bn * Rn * 5;
  float* o_roi = out + (size_t)Bn * Rn * 7;
  float* o_mis = out + (size_t)Bn * Rn * 12;

  if (tid < Rn) {
    int s = tid;
    bool is_pos = s < n_pos;
    bool is_real = s < n_pos + n_neg;
    float d0 = 0, d1 = 0, d2 = 0, d3 = 0, d4 = 0, c0 = 0, c1 = 0;
    float r0 = 0, r1 = 0, r2 = 0, r3 = 0, r4 = 0;
    if (is_real) {
      int pos_in_sorted = is_pos ? s : (npos + (s - n_pos));
      int p = (int)sidx[pos_in_sorted];
      const float* pb = pr + (bp + p) * 5;
      float q0 = pb[0], q1 = pb[1], q2 = pb[2], q3 = pb[3];
      r0 = q0; r1 = q1; r2 = q2; r3 = q3; r4 = 1.0f; c1 = 1.0f;
      if (is_pos) {
        int g = parg[bp + p];
        const float* gb = gt + ((size_t)b * Gn + g) * 5;
        float g0 = gb[0], g1 = gb[1], g2 = gb[2], g3 = gb[3];
        float h = __fsub_rn(q2, q0), w = __fsub_rn(q3, q1);
        float gh = __fsub_rn(g2, g0), gw = __fsub_rn(g3, g1);
        float cy = __fmul_rn(__fadd_rn(q2, q0), 0.5f);
        float cx = __fmul_rn(__fadd_rn(q3, q1), 0.5f);
        float gcy = __fmul_rn(__fadd_rn(g2, g0), 0.5f);
        float gcx = __fmul_rn(__fadd_rn(g3, g1), 0.5f);
        float dy = __fdiv_rn(__fsub_rn(gcy, cy), h);
        float dx = __fdiv_rn(__fsub_rn(gcx, cx), w);
        float dh = logf(fmaxf(__fdiv_rn(gh, h), 1e-8f));
        float dw = logf(fmaxf(__fdiv_rn(gw, w), 1e-8f));
        d0 = __fdiv_rn(dy, 0.1f); d1 = __fdiv_rn(dx, 0.1f);
        d2 = __fdiv_rn(dh, 0.2f); d3 = __fdiv_rn(dw, 0.2f);
        d4 = 1.0f;
        c0 = (float)gtc[((size_t)b * Gn + g) * 2];
      } else {
        d4 = -1.0f;
      }
    }
    size_t ob = (size_t)b * Rn + s;
    o_del[ob * 5 + 0] = d0; o_del[ob * 5 + 1] = d1; o_del[ob * 5 + 2] = d2;
    o_del[ob * 5 + 3] = d3; o_del[ob * 5 + 4] = d4;
    o_cls[ob * 2 + 0] = c0; o_cls[ob * 2 + 1] = c1;
    o_roi[ob * 5 + 0] = r0; o_roi[ob * 5 + 1] = r1; o_roi[ob * 5 + 2] = r2;
    o_roi[ob * 5 + 3] = r3; o_roi[ob * 5 + 4] = r4;
  }

  if (tid < Gn) {
    float gv = gt[((size_t)b * Gn + tid) * 5 + 4];
    if (gv != 0.0f && matched[tid] == 0) atomicAdd(&s_miss, 1);
  }
  __syncthreads();
  if (tid == 0) o_mis[b] = (float)s_miss;
}

extern "C" void kernel_launch(void* const* d_in, const int* in_sizes, int n_in,
                              void* d_out, int out_size, void* d_ws, size_t ws_size,
                              hipStream_t stream) {
  const float* gt = (const float*)d_in[0];
  const int* gtc = (const int*)d_in[1];
  const float* pr = (const float*)d_in[2];
  float* out = (float*)d_out;

  int* removed = (int*)d_ws;                 // B*P ints
  int* parg = removed + Bn * Pn;             // B*P ints
  float* pmax = (float*)(parg + Bn * Pn);    // B*P floats

  hipMemsetAsync(removed, 0, (size_t)Bn * Pn * sizeof(int), stream);
  k_rowmax<<<Bn * Gn, 64, 0, stream>>>(gt, pr, removed);
  k_colstats<<<dim3((Pn + 255) / 256, Bn), 256, 0, stream>>>(gt, pr, pmax, parg);
  k_select<<<Bn, 1024, 0, stream>>>(gt, gtc, pr, removed, pmax, parg, out);
}

// Round 3
// 121.325 us; speedup vs baseline: 2.6247x; 2.6247x over previous
//
#include <hip/hip_runtime.h>
#include <stdint.h>

#define Bn 16
#define Gn 128
#define Pn 8000
#define Rn 200
#define POSCAP 66
#define CANDN 1024

typedef unsigned long long u64;

// Exact JAX threefry2x32 block (jax/_src/prng.py rotation schedule).
__device__ __forceinline__ void tf2x32(uint32_t k0, uint32_t k1,
                                       uint32_t x0, uint32_t x1,
                                       uint32_t& y0, uint32_t& y1) {
  uint32_t ks0 = k0, ks1 = k1, ks2 = k0 ^ k1 ^ 0x1BD11BDAu;
  x0 += ks0; x1 += ks1;
#define TF_ROUND(r) { x0 += x1; x1 = (x1 << (r)) | (x1 >> (32 - (r))); x1 ^= x0; }
  TF_ROUND(13) TF_ROUND(15) TF_ROUND(26) TF_ROUND(6)
  x0 += ks1; x1 += ks2 + 1u;
  TF_ROUND(17) TF_ROUND(29) TF_ROUND(16) TF_ROUND(24)
  x0 += ks2; x1 += ks0 + 2u;
  TF_ROUND(13) TF_ROUND(15) TF_ROUND(26) TF_ROUND(6)
  x0 += ks0; x1 += ks1 + 3u;
  TF_ROUND(17) TF_ROUND(29) TF_ROUND(16) TF_ROUND(24)
  x0 += ks1; x1 += ks2 + 4u;
  TF_ROUND(13) TF_ROUND(15) TF_ROUND(26) TF_ROUND(6)
  x0 += ks2; x1 += ks0 + 5u;
#undef TF_ROUND
  y0 = x0; y1 = x1;
}

// IoU, bit-exact vs reference float32 (no FMA contraction).
__device__ __forceinline__ float iou_f(float g0, float g1, float g2, float g3, float ag,
                                       float p0, float p1, float p2, float p3) {
  float iw = fmaxf(0.0f, __fsub_rn(fminf(g3, p3), fmaxf(g1, p1)));
  float ih = fmaxf(0.0f, __fsub_rn(fminf(g2, p2), fmaxf(g0, p0)));
  float inter = __fmul_rn(iw, ih);
  float ap = __fmul_rn(__fsub_rn(p3, p1), __fsub_rn(p2, p0));
  return __fdiv_rn(inter, __fsub_rn(__fadd_rn(ag, ap), inter));
}

// Fused: per-proposal col max/argmax (tie->lowest g) + per-GT row argmax
// (tie->lowest p) via packed (fbits(iou)<<32 | ~p) atomicMax. iou>=0 for all
// valid pairs, so init 0 never wins spuriously.
__global__ __launch_bounds__(256) void k_iou(const float* __restrict__ gt,
                                             const float* __restrict__ pr,
                                             float* __restrict__ pmax,
                                             int* __restrict__ parg,
                                             u64* __restrict__ rowpk) {
  __shared__ float sg[Gn * 5];
  __shared__ u64 srow[Gn];
  int b = blockIdx.y, tid = threadIdx.x;
  for (int i = tid; i < Gn * 5; i += 256) sg[i] = gt[(size_t)b * Gn * 5 + i];
  for (int i = tid; i < Gn; i += 256) srow[i] = 0ull;
  __syncthreads();
  int p = blockIdx.x * 256 + tid;
  float p0 = 0, p1 = 0, p2 = 0, p3 = 0, pv = 0;
  if (p < Pn) {
    const float* pb = pr + ((size_t)b * Pn + p) * 5;
    p0 = pb[0]; p1 = pb[1]; p2 = pb[2]; p3 = pb[3]; pv = pb[4];
  }
  bool valid = (p < Pn) && (pv != 0.0f);
  float best = -2.0f; int bidx = 0;
  int g0 = tid & (Gn - 1);  // rotate start: no intra-wave atomic address clash
  for (int it = 0; it < Gn; it++) {
    int g = (g0 + it) & (Gn - 1);
    const float* gb = sg + g * 5;
    if (valid && gb[4] != 0.0f) {
      float ag = __fmul_rn(__fsub_rn(gb[3], gb[1]), __fsub_rn(gb[2], gb[0]));
      float v = iou_f(gb[0], gb[1], gb[2], gb[3], ag, p0, p1, p2, p3);
      if (v > best || (v == best && g < bidx)) { best = v; bidx = g; }
      u64 key = ((u64)__float_as_uint(v) << 32) | (unsigned)(~p);
      atomicMax(&srow[g], key);
    }
  }
  __syncthreads();
  for (int i = tid; i < Gn; i += 256) {
    u64 v = srow[i];
    if (v) atomicMax(&rowpk[(size_t)b * Gn + i], v);
  }
  if (p < Pn) {
    pmax[(size_t)b * Pn + p] = best;
    parg[(size_t)b * Pn + p] = bidx;
  }
}

// Per-batch: removed bitmap from row winners, PRNG+classify+histogram,
// threshold scan, candidate gather, 1024-wide bitonic sort, epilogue.
__global__ __launch_bounds__(1024) void k_select(
    const float* __restrict__ gt, const int* __restrict__ gtc,
    const float* __restrict__ pr, const float* __restrict__ pmax,
    const int* __restrict__ parg, const u64* __restrict__ rowpk,
    float* __restrict__ out) {
  __shared__ uint32_t skey[Pn];           // 32 KB: (cls<<23)|val23
  __shared__ uint32_t hist2[1024];
  __shared__ uint32_t hist1[1024];
  __shared__ u64 cand[CANDN];             // 8 KB
  __shared__ uint32_t rembm[Pn / 32 + 1];
  __shared__ int matched[Gn];
  __shared__ int s_npos, s_nneg, s_miss, s_call, s_cpos, s_T2, s_T1;
  __shared__ uint32_t s_keys[4];
  int b = blockIdx.x, tid = threadIdx.x;

  hist2[tid] = 0; hist1[tid] = 0; cand[tid] = 0ull;
  if (tid < Pn / 32 + 1) rembm[tid] = 0;
  if (tid < Gn) matched[tid] = 0;
  if (tid == 0) {
    s_npos = 0; s_nneg = 0; s_miss = 0; s_call = 0; s_cpos = 0;
    s_T2 = 1025; s_T1 = 1025;
    // partitionable threefry: keys=split((0,42),16)[b]=tf(...,0,b); k1,k2=split
    uint32_t kb0, kb1, a0, a1, c0, c1;
    tf2x32(0u, 42u, 0u, (uint32_t)b, kb0, kb1);
    tf2x32(kb0, kb1, 0u, 0u, a0, a1);
    tf2x32(kb0, kb1, 0u, 1u, c0, c1);
    s_keys[0] = a0; s_keys[1] = a1; s_keys[2] = c0; s_keys[3] = c1;
  }
  __syncthreads();

  if (tid < Gn) {
    float gv = gt[((size_t)b * Gn + tid) * 5 + 4];
    u64 pk = rowpk[(size_t)b * Gn + tid];
    if (gv != 0.0f && pk != 0ull) {
      unsigned p = ~(unsigned)(pk & 0xFFFFFFFFull);
      atomicOr(&rembm[p >> 5], 1u << (p & 31));
    }
  }
  __syncthreads();

  uint32_t k10 = s_keys[0], k11 = s_keys[1], k20 = s_keys[2], k21 = s_keys[3];
  const size_t bp = (size_t)b * Pn;
  int lpos = 0, lneg = 0;
  for (int p = tid; p < Pn; p += 1024) {
    float pv = pr[(bp + p) * 5 + 4];
    int rem = (rembm[p >> 5] >> (p & 31)) & 1;
    float pm = pmax[bp + p];
    int cls = 0;
    if (pv != 0.0f && !rem) cls = (pm >= 0.5f) ? 2 : 1;
    uint32_t key = 0;
    if (cls) {
      uint32_t kk0 = (cls == 2) ? k10 : k20, kk1 = (cls == 2) ? k11 : k21;
      uint32_t y0, y1;
      tf2x32(kk0, kk1, 0u, (uint32_t)p, y0, y1);
      uint32_t val = (y0 ^ y1) >> 9;
      key = ((uint32_t)cls << 23) | val;
      if (cls == 2) { lpos++; matched[parg[bp + p]] = 1; atomicAdd(&hist2[val >> 13], 1u); }
      else { lneg++; atomicAdd(&hist1[val >> 13], 1u); }
    }
    skey[p] = key;
  }
  if (lpos) atomicAdd(&s_npos, lpos);
  if (lneg) atomicAdd(&s_nneg, lneg);
  __syncthreads();

  // threshold scan: wave0 -> positives, wave1 -> negatives
  if (tid < 128) {
    bool isP = tid < 64;
    int lane = tid & 63;
    uint32_t* hist = isP ? hist2 : hist1;
    int cnt = isP ? s_npos : s_nneg;
    int cap = isP ? POSCAP : Rn;
    int need = cnt < cap ? cnt : cap;
    int base = 1024 - 16 * (lane + 1);
    int local = 0;
#pragma unroll
    for (int j = 0; j < 16; j++) local += (int)hist[base + j];
    int incl = local;
    for (int d = 1; d < 64; d <<= 1) {
      int o = __shfl_up(incl, d);
      if (lane >= d) incl += o;
    }
    int above = incl - local;  // count in buckets strictly above this range
    if (need > 0 && above < need && above + local >= need) {
      int cum = above, T = base;
      for (int j = 15; j >= 0; j--) {
        cum += (int)hist[base + j];
        if (cum >= need) { T = base + j; break; }
      }
      if (isP) s_T2 = T; else s_T1 = T;
    }
  }
  __syncthreads();
  int T2 = s_T2, T1 = s_T1;

  for (int p = tid; p < Pn; p += 1024) {
    uint32_t key = skey[p];
    int cls = (int)(key >> 23);
    if (cls) {
      int bucket = (int)((key & 0x7FFFFFu) >> 13);
      int T = (cls == 2) ? T2 : T1;
      if (bucket >= T) {
        int slot = atomicAdd(&s_call, 1);
        if (slot < CANDN) {
          cand[slot] = ((u64)key << 16) | (uint32_t)((uint16_t)(~p));
          if (cls == 2) atomicAdd(&s_cpos, 1);
        }
      }
    }
  }
  __syncthreads();

  // bitonic sort desc on u64 (strict total order: cls, val desc, idx asc)
  for (unsigned k = 2; k <= CANDN; k <<= 1) {
    for (unsigned j = k >> 1; j > 0; j >>= 1) {
      unsigned i = tid, l = i ^ j;
      if (l > i) {
        u64 av = cand[i], cv = cand[l];
        bool a_first = av > cv;
        bool desc = ((i & k) == 0u);
        if (desc != a_first) { cand[i] = cv; cand[l] = av; }
      }
      __syncthreads();
    }
  }

  int npos = s_npos, nneg = s_nneg, cpos = s_cpos;
  int n_pos = npos < POSCAP ? npos : POSCAP;
  int rems = Rn - n_pos;
  int n_neg = nneg < rems ? nneg : rems;

  float* o_del = out;
  float* o_cls = out + (size_t)Bn * Rn * 5;
  float* o_roi = out + (size_t)Bn * Rn * 7;
  float* o_mis = out + (size_t)Bn * Rn * 12;

  if (tid < Rn) {
    int s = tid;
    bool is_pos = s < n_pos;
    bool is_real = s < n_pos + n_neg;
    float d0 = 0, d1 = 0, d2 = 0, d3 = 0, d4 = 0, c0 = 0, c1 = 0;
    float r0 = 0, r1 = 0, r2 = 0, r3 = 0, r4 = 0;
    if (is_real) {
      int ci = is_pos ? s : (cpos + (s - n_pos));
      u64 ck = cand[ci];
      int p = (int)((~(unsigned)ck) & 0xFFFFu);
      const float* pb = pr + (bp + p) * 5;
      float q0 = pb[0], q1 = pb[1], q2 = pb[2], q3 = pb[3];
      r0 = q0; r1 = q1; r2 = q2; r3 = q3; r4 = 1.0f; c1 = 1.0f;
      if (is_pos) {
        int g = parg[bp + p];
        const float* gb = gt + ((size_t)b * Gn + g) * 5;
        float g0 = gb[0], g1 = gb[1], g2 = gb[2], g3 = gb[3];
        float h = __fsub_rn(q2, q0), w = __fsub_rn(q3, q1);
        float gh = __fsub_rn(g2, g0), gw = __fsub_rn(g3, g1);
        float cy = __fmul_rn(__fadd_rn(q2, q0), 0.5f);
        float cx = __fmul_rn(__fadd_rn(q3, q1), 0.5f);
        float gcy = __fmul_rn(__fadd_rn(g2, g0), 0.5f);
        float gcx = __fmul_rn(__fadd_rn(g3, g1), 0.5f);
        float dy = __fdiv_rn(__fsub_rn(gcy, cy), h);
        float dx = __fdiv_rn(__fsub_rn(gcx, cx), w);
        float dh = logf(fmaxf(__fdiv_rn(gh, h), 1e-8f));
        float dw = logf(fmaxf(__fdiv_rn(gw, w), 1e-8f));
        d0 = __fdiv_rn(dy, 0.1f); d1 = __fdiv_rn(dx, 0.1f);
        d2 = __fdiv_rn(dh, 0.2f); d3 = __fdiv_rn(dw, 0.2f);
        d4 = 1.0f;
        c0 = (float)gtc[((size_t)b * Gn + g) * 2];
      } else {
        d4 = -1.0f;
      }
    }
    size_t ob = (size_t)b * Rn + s;
    o_del[ob * 5 + 0] = d0; o_del[ob * 5 + 1] = d1; o_del[ob * 5 + 2] = d2;
    o_del[ob * 5 + 3] = d3; o_del[ob * 5 + 4] = d4;
    o_cls[ob * 2 + 0] = c0; o_cls[ob * 2 + 1] = c1;
    o_roi[ob * 5 + 0] = r0; o_roi[ob * 5 + 1] = r1; o_roi[ob * 5 + 2] = r2;
    o_roi[ob * 5 + 3] = r3; o_roi[ob * 5 + 4] = r4;
  }

  if (tid < Gn) {
    float gv = gt[((size_t)b * Gn + tid) * 5 + 4];
    if (gv != 0.0f && matched[tid] == 0) atomicAdd(&s_miss, 1);
  }
  __syncthreads();
  if (tid == 0) o_mis[b] = (float)s_miss;
}

extern "C" void kernel_launch(void* const* d_in, const int* in_sizes, int n_in,
                              void* d_out, int out_size, void* d_ws, size_t ws_size,
                              hipStream_t stream) {
  const float* gt = (const float*)d_in[0];
  const int* gtc = (const int*)d_in[1];
  const float* pr = (const float*)d_in[2];
  float* out = (float*)d_out;

  u64* rowpk = (u64*)d_ws;                        // B*G u64 = 16 KB
  float* pmax = (float*)(rowpk + Bn * Gn);        // B*P floats
  int* parg = (int*)(pmax + (size_t)Bn * Pn);     // B*P ints

  hipMemsetAsync(rowpk, 0, (size_t)Bn * Gn * sizeof(u64), stream);
  k_iou<<<dim3((Pn + 255) / 256, Bn), 256, 0, stream>>>(gt, pr, pmax, parg, rowpk);
  k_select<<<Bn, 1024, 0, stream>>>(gt, gtc, pr, pmax, parg, rowpk, out);
}